// Round 1
// baseline (430.348 us; speedup 1.0000x reference)
//
#include <hip/hip_runtime.h>
#include <math.h>

#define B_  4
#define T_  16
#define C_  64
#define CQ_ 8
#define HW_ 9216          // 96*96
#define NCHUNK_ 288       // HW_/32

// ---------------------------------------------------------------------------
// K1: partial energies. grid (288, 4), block 512 = (t=16 x g=32).
// Each thread computes q[t][0:8], k[t][0:8] for its (t, g) directly from x
// (3 temporal taps, zero-padded), stages them in LDS, then threads remap to
// (t,s) pairs and dot over (cq, g) -> per-chunk partial energy.
// ---------------------------------------------------------------------------
__global__ __launch_bounds__(512, 2)
void k_energy(const float* __restrict__ x, const float* __restrict__ wq,
              const float* __restrict__ bq, const float* __restrict__ wk,
              const float* __restrict__ bk, float* __restrict__ partE) {
  __shared__ __attribute__((aligned(16))) float WQs[64 * 24];
  __shared__ __attribute__((aligned(16))) float WKs[64 * 24];
  // Q/K layout: [g][t][12] with per-g stride 196 floats (stride%32==4 breaks
  // the 16*12%32==0 bank cycle; 196*4B is 16B-aligned for float4 reads).
  __shared__ __attribute__((aligned(16))) float QK[2 * 32 * 196];
  __shared__ float Etmp[256];

  const int b   = blockIdx.y;
  const int hw0 = blockIdx.x * 32;
  const int tid = threadIdx.x;

  // stage conv weights: wq[cqi][ci][d] -> WQs[ci*24 + cqi*3 + d]
  for (int i = tid; i < CQ_ * C_ * 3; i += 512) {
    int cqi = i / (C_ * 3), r = i % (C_ * 3);
    int ci = r / 3, d = r % 3;
    WQs[ci * 24 + cqi * 3 + d] = wq[i];
    WKs[ci * 24 + cqi * 3 + d] = wk[i];
  }
  __syncthreads();

  const int t = tid >> 5;   // 0..15
  const int g = tid & 31;   // 0..31
  const float* xb = x + (size_t)(b * T_ * C_) * HW_ + hw0 + g;

  float qa[CQ_], ka[CQ_];
#pragma unroll
  for (int j = 0; j < CQ_; ++j) { qa[j] = 0.f; ka[j] = 0.f; }

  for (int ci = 0; ci < C_; ++ci) {
    float xm = 0.f, xp = 0.f;
    if (t > 0)      xm = xb[(size_t)((t - 1) * C_ + ci) * HW_];
    float x0 =           xb[(size_t)(t * C_ + ci) * HW_];
    if (t < T_ - 1) xp = xb[(size_t)((t + 1) * C_ + ci) * HW_];
    const float* wqc = &WQs[ci * 24];
    const float* wkc = &WKs[ci * 24];
#pragma unroll
    for (int j = 0; j < CQ_; ++j) {
      qa[j] += wqc[j * 3 + 0] * xm + wqc[j * 3 + 1] * x0 + wqc[j * 3 + 2] * xp;
      ka[j] += wkc[j * 3 + 0] * xm + wkc[j * 3 + 1] * x0 + wkc[j * 3 + 2] * xp;
    }
  }
#pragma unroll
  for (int j = 0; j < CQ_; ++j) { qa[j] += bq[j]; ka[j] += bk[j]; }

  float* Qs = &QK[0];
  float* Ks = &QK[32 * 196];
#pragma unroll
  for (int j = 0; j < CQ_; ++j) {
    Qs[g * 196 + t * 12 + j] = qa[j];
    Ks[g * 196 + t * 12 + j] = ka[j];
  }
  __syncthreads();

  // E-dot: thread -> (h, tt, ss); h splits the 32 g's in half.
  const int h  = tid >> 8;
  const int tt = (tid >> 4) & 15;
  const int ss = tid & 15;
  float e = 0.f;
  for (int gg = h * 16; gg < h * 16 + 16; ++gg) {
    const float4 q0 = *(const float4*)&Qs[gg * 196 + tt * 12];
    const float4 q1 = *(const float4*)&Qs[gg * 196 + tt * 12 + 4];
    const float4 k0 = *(const float4*)&Ks[gg * 196 + ss * 12];
    const float4 k1 = *(const float4*)&Ks[gg * 196 + ss * 12 + 4];
    e += q0.x * k0.x + q0.y * k0.y + q0.z * k0.z + q0.w * k0.w
       + q1.x * k1.x + q1.y * k1.y + q1.z * k1.z + q1.w * k1.w;
  }
  if (h == 1) Etmp[tt * 16 + ss] = e;
  __syncthreads();
  if (h == 0) {
    e += Etmp[tt * 16 + ss];
    partE[((size_t)(b * NCHUNK_ + blockIdx.x)) * 256 + tt * 16 + ss] = e;
  }
}

// ---------------------------------------------------------------------------
// K1b: reduce 288 partials and softmax over s. grid 4, block 256 (t*16+s).
// ---------------------------------------------------------------------------
__global__ __launch_bounds__(256)
void k_softmax(const float* __restrict__ partE, float* __restrict__ heat) {
  const int b = blockIdx.x;
  const int tid = threadIdx.x;
  float e = 0.f;
  for (int ch = 0; ch < NCHUNK_; ++ch)
    e += partE[((size_t)(b * NCHUNK_ + ch)) * 256 + tid];
  // softmax across the 16 s-lanes (tid%16): lanes tid%64 group as 4t x 16s.
  float mx = e;
#pragma unroll
  for (int m = 1; m < 16; m <<= 1) mx = fmaxf(mx, __shfl_xor(mx, m, 64));
  float ex = expf(e - mx);
  float sm = ex;
#pragma unroll
  for (int m = 1; m < 16; m <<= 1) sm += __shfl_xor(sm, m, 64);
  heat[b * 256 + tid] = ex / sm;
}

// ---------------------------------------------------------------------------
// K2a: temporal mix. xh[b,t,ci,g] = sum_s heat[b,t,s] * x[b,s,ci,g]
// grid (36, 64, 4), block 256. Output written to d_out (scratch use).
// ---------------------------------------------------------------------------
__global__ __launch_bounds__(256)
void k_tmix(const float* __restrict__ x, const float* __restrict__ heat,
            float* __restrict__ xh) {
  __shared__ float hs[256];
  const int b = blockIdx.z;
  const int ci = blockIdx.y;
  const int g = blockIdx.x * 256 + threadIdx.x;
  hs[threadIdx.x] = heat[b * 256 + threadIdx.x];
  __syncthreads();

  const float* xp = x + (size_t)(b * T_ * C_ + ci) * HW_ + g;
  float xv[T_];
#pragma unroll
  for (int s = 0; s < T_; ++s) xv[s] = xp[(size_t)s * C_ * HW_];

  float* op = xh + (size_t)(b * T_ * C_ + ci) * HW_ + g;
#pragma unroll
  for (int t = 0; t < T_; ++t) {
    const float* hr = &hs[t * 16];
    float acc = 0.f;
#pragma unroll
    for (int s = 0; s < T_; ++s) acc += hr[s] * xv[s];
    op[(size_t)t * C_ * HW_] = acc;
  }
}

// ---------------------------------------------------------------------------
// K2b: channel mix + residual, in-place on d_out.
// out[b,t,c,g] = gamma*(sum_ci Wv[c,ci]*xh[b,t,ci,g] + bv[c]) + x[b,t,c,g]
// grid (36, 16, 4), block 256. Each thread owns one (b,t,g) column: reads all
// 64 ci of that column, then overwrites the same 64 addresses -> race-free.
// ---------------------------------------------------------------------------
__global__ __launch_bounds__(256)
void k_cmix(const float* __restrict__ x, const float* __restrict__ wv,
            const float* __restrict__ bv, const float* __restrict__ gam,
            float* io) {
  __shared__ __attribute__((aligned(16))) float WvT[64 * 64];
  __shared__ float bvs[64];
  const int b = blockIdx.z;
  const int t = blockIdx.y;
  const int g = blockIdx.x * 256 + threadIdx.x;

  for (int i = threadIdx.x; i < 4096; i += 256) {
    int c = i >> 6, ci = i & 63;
    WvT[ci * 64 + c] = wv[i];   // wv[c][ci] -> WvT[ci][c]
  }
  if (threadIdx.x < 64) bvs[threadIdx.x] = bv[threadIdx.x];
  __syncthreads();

  const float gamma = gam[0];
  float acc[64];
#pragma unroll
  for (int c = 0; c < 64; ++c) acc[c] = 0.f;

  const float* xhp = io + (size_t)(b * T_ + t) * C_ * HW_ + g;
  for (int ci = 0; ci < 64; ++ci) {
    float v = xhp[(size_t)ci * HW_];
    const float4* wrow = (const float4*)&WvT[ci * 64];
#pragma unroll
    for (int c4 = 0; c4 < 16; ++c4) {
      float4 w = wrow[c4];
      acc[c4 * 4 + 0] += w.x * v;
      acc[c4 * 4 + 1] += w.y * v;
      acc[c4 * 4 + 2] += w.z * v;
      acc[c4 * 4 + 3] += w.w * v;
    }
  }

  const float* xp = x + (size_t)(b * T_ + t) * C_ * HW_ + g;
  float* op = io + (size_t)(b * T_ + t) * C_ * HW_ + g;
#pragma unroll
  for (int c = 0; c < 64; ++c) {
    float res = xp[(size_t)c * HW_];
    op[(size_t)c * HW_] = gamma * (acc[c] + bvs[c]) + res;
  }
}

// ---------------------------------------------------------------------------
extern "C" void kernel_launch(void* const* d_in, const int* in_sizes, int n_in,
                              void* d_out, int out_size, void* d_ws, size_t ws_size,
                              hipStream_t stream) {
  const float* x   = (const float*)d_in[0];
  const float* wq  = (const float*)d_in[1];
  const float* bq  = (const float*)d_in[2];
  const float* wk  = (const float*)d_in[3];
  const float* bk  = (const float*)d_in[4];
  const float* wv  = (const float*)d_in[5];
  const float* bv  = (const float*)d_in[6];
  const float* gam = (const float*)d_in[7];
  float* out = (float*)d_out;

  float* partE = (float*)d_ws;                       // 4*288*256 floats
  float* heat  = partE + (size_t)B_ * NCHUNK_ * 256; // 4*16*16 floats

  k_energy <<<dim3(NCHUNK_, B_), 512, 0, stream>>>(x, wq, bq, wk, bk, partE);
  k_softmax<<<dim3(B_),         256, 0, stream>>>(partE, heat);
  k_tmix   <<<dim3(36, C_, B_), 256, 0, stream>>>(x, heat, out);
  k_cmix   <<<dim3(36, T_, B_), 256, 0, stream>>>(x, wv, bv, gam, out);
}

// Round 2
// 314.824 us; speedup vs baseline: 1.3669x; 1.3669x over previous
//
#include <hip/hip_runtime.h>
#include <math.h>

#define B_  4
#define T_  16
#define C_  64
#define CQ_ 8
#define HW_ 9216          // 96*96
#define NCHUNK_ 288       // HW_/32

// ws layout (floats): WT[2][64][32] @ 0 ; partE @ 4096 ; heat @ 4096 + B*288*256

// ---------------------------------------------------------------------------
// k_prep: transpose conv weights so each ci's row (8 cq x 3 taps = 24 floats)
// is contiguous (stride 32) -> enables s_load_dwordx16 scalar fetches.
// ---------------------------------------------------------------------------
__global__ __launch_bounds__(256)
void k_prep(const float* __restrict__ wq, const float* __restrict__ wk,
            float* __restrict__ WT) {
  for (int j = threadIdx.x; j < CQ_ * C_ * 3; j += 256) {
    int ci = j / 24, r = j % 24;      // r = cqi*3 + d
    int cqi = r / 3, d = r % 3;
    WT[ci * 32 + r]        = wq[(cqi * C_ + ci) * 3 + d];
    WT[2048 + ci * 32 + r] = wk[(cqi * C_ + ci) * 3 + d];
  }
}

// ---------------------------------------------------------------------------
// k_energy: partial energies. grid (288, 4), block 512 = (t=16 x g=32).
// Conv weights come from global via wave-uniform (scalar) loads — no LDS.
// ---------------------------------------------------------------------------
__global__ __launch_bounds__(512, 4)
void k_energy(const float* __restrict__ x, const float* __restrict__ WT,
              const float* __restrict__ bq, const float* __restrict__ bk,
              float* __restrict__ partE) {
  // Q/K layout: [g][t][12], per-g stride 196 (breaks 16*12%32==0 bank cycle)
  __shared__ __attribute__((aligned(16))) float QK[2 * 32 * 196];
  __shared__ float Etmp[256];

  const int b   = blockIdx.y;
  const int hw0 = blockIdx.x * 32;
  const int tid = threadIdx.x;
  const int t = tid >> 5;   // 0..15
  const int g = tid & 31;   // 0..31
  const float* xb  = x + (size_t)(b * T_ * C_) * HW_ + hw0 + g;
  const float* wqt = WT;           // [ci*32 + cqi*3 + d]
  const float* wkt = WT + 2048;

  float qa[CQ_], ka[CQ_];
#pragma unroll
  for (int j = 0; j < CQ_; ++j) { qa[j] = 0.f; ka[j] = 0.f; }

#pragma unroll 2
  for (int ci = 0; ci < C_; ++ci) {
    float xm = 0.f, xp = 0.f;
    if (t > 0)      xm = xb[(size_t)((t - 1) * C_ + ci) * HW_];
    float x0 =           xb[(size_t)(t * C_ + ci) * HW_];
    if (t < T_ - 1) xp = xb[(size_t)((t + 1) * C_ + ci) * HW_];
    const float* wq_r = &wqt[ci * 32];
    const float* wk_r = &wkt[ci * 32];
#pragma unroll
    for (int j = 0; j < CQ_; ++j) {
      qa[j] += wq_r[j * 3 + 0] * xm + wq_r[j * 3 + 1] * x0 + wq_r[j * 3 + 2] * xp;
      ka[j] += wk_r[j * 3 + 0] * xm + wk_r[j * 3 + 1] * x0 + wk_r[j * 3 + 2] * xp;
    }
  }
#pragma unroll
  for (int j = 0; j < CQ_; ++j) { qa[j] += bq[j]; ka[j] += bk[j]; }

  float* Qs = &QK[0];
  float* Ks = &QK[32 * 196];
#pragma unroll
  for (int j = 0; j < CQ_; ++j) {
    Qs[g * 196 + t * 12 + j] = qa[j];
    Ks[g * 196 + t * 12 + j] = ka[j];
  }
  __syncthreads();

  // E-dot: thread -> (h, tt, ss); h splits the 32 g's in half.
  const int h  = tid >> 8;
  const int tt = (tid >> 4) & 15;
  const int ss = tid & 15;
  float e = 0.f;
  for (int gg = h * 16; gg < h * 16 + 16; ++gg) {
    const float4 q0 = *(const float4*)&Qs[gg * 196 + tt * 12];
    const float4 q1 = *(const float4*)&Qs[gg * 196 + tt * 12 + 4];
    const float4 k0 = *(const float4*)&Ks[gg * 196 + ss * 12];
    const float4 k1 = *(const float4*)&Ks[gg * 196 + ss * 12 + 4];
    e += q0.x * k0.x + q0.y * k0.y + q0.z * k0.z + q0.w * k0.w
       + q1.x * k1.x + q1.y * k1.y + q1.z * k1.z + q1.w * k1.w;
  }
  if (h == 1) Etmp[tt * 16 + ss] = e;
  __syncthreads();
  if (h == 0) {
    e += Etmp[tt * 16 + ss];
    partE[((size_t)(b * NCHUNK_ + blockIdx.x)) * 256 + tt * 16 + ss] = e;
  }
}

// ---------------------------------------------------------------------------
// k_softmax: reduce 288 partials and softmax over s. grid 4, block 256.
// ---------------------------------------------------------------------------
__global__ __launch_bounds__(256)
void k_softmax(const float* __restrict__ partE, float* __restrict__ heat) {
  const int b = blockIdx.x;
  const int tid = threadIdx.x;
  float e = 0.f;
  for (int ch = 0; ch < NCHUNK_; ++ch)
    e += partE[((size_t)(b * NCHUNK_ + ch)) * 256 + tid];
  float mx = e;
#pragma unroll
  for (int m = 1; m < 16; m <<= 1) mx = fmaxf(mx, __shfl_xor(mx, m, 64));
  float ex = expf(e - mx);
  float sm = ex;
#pragma unroll
  for (int m = 1; m < 16; m <<= 1) sm += __shfl_xor(sm, m, 64);
  heat[b * 256 + tid] = ex / sm;
}

// ---------------------------------------------------------------------------
// k_mix: fused tmix + cmix + residual.
//   out[b,t,c,g] = gamma*( sum_ci Wv[c,ci] * sum_s heat[t,s] x[b,s,ci,g]
//                          + bv[c] ) + x[b,t,c,g]
// grid (576, 4), block 256 = (t=16 x g=16). x-tile staged in LDS transposed
// to [s][g][ci] (stride 68) so xh accumulates via b128 reads along ci.
// Wv rows are read with wave-uniform indices -> scalar loads, zero LDS.
// ---------------------------------------------------------------------------
__global__ __launch_bounds__(256, 2)
void k_mix(const float* __restrict__ x, const float* __restrict__ heat,
           const float* __restrict__ wv, const float* __restrict__ bv,
           const float* __restrict__ gam, float* __restrict__ out) {
  __shared__ __attribute__((aligned(16))) float xs[16 * 16 * 68]; // [s][g][ci]
  __shared__ float hs[256];

  const int b   = blockIdx.y;
  const int hw0 = blockIdx.x * 16;
  const int tid = threadIdx.x;

  hs[tid] = heat[b * 256 + tid];

  // stage x[b, :, :, hw0:hw0+16] -> xs[s][g][ci]  (transpose g<->ci)
  const float* xbase = x + (size_t)(b * T_ * C_) * HW_ + hw0;
#pragma unroll
  for (int kk = 0; kk < 16; ++kk) {
    int slot = kk * 256 + tid;        // 0..4095
    int row  = slot >> 2;             // s*64 + ci
    int quad = slot & 3;              // which 4 g's
    int s = row >> 6, ci = row & 63;
    float4 v = *(const float4*)(xbase + (size_t)row * HW_ + quad * 4);
    float* dst = &xs[(s * 16 + quad * 4) * 68 + ci];
    dst[0 * 68] = v.x;
    dst[1 * 68] = v.y;
    dst[2 * 68] = v.z;
    dst[3 * 68] = v.w;
  }
  __syncthreads();

  const int t = tid >> 4;   // 0..15
  const int g = tid & 15;   // 0..15

  float h[T_];
#pragma unroll
  for (int s = 0; s < T_; ++s) h[s] = hs[t * 16 + s];

  // xh[ci] = sum_s h[s] * x[s,ci,g]
  float xh[C_];
#pragma unroll
  for (int cq = 0; cq < 16; ++cq) {
    float ax = 0.f, ay = 0.f, az = 0.f, aw = 0.f;
#pragma unroll
    for (int s = 0; s < T_; ++s) {
      const float4 v = *(const float4*)&xs[(s * 16 + g) * 68 + cq * 4];
      ax += h[s] * v.x; ay += h[s] * v.y; az += h[s] * v.z; aw += h[s] * v.w;
    }
    xh[cq * 4 + 0] = ax; xh[cq * 4 + 1] = ay;
    xh[cq * 4 + 2] = az; xh[cq * 4 + 3] = aw;
  }

  // c-mix with scalar-loaded weights + bias + residual
  const float gamma = gam[0];
  const float* xr = x   + ((size_t)(b * T_ + t) * C_) * HW_ + hw0 + g;
  float*       op = out + ((size_t)(b * T_ + t) * C_) * HW_ + hw0 + g;
  for (int c = 0; c < C_; ++c) {
    const float* wr = wv + c * C_;     // wave-uniform -> s_load
    float o = 0.f;
#pragma unroll
    for (int ci = 0; ci < C_; ++ci) o += wr[ci] * xh[ci];
    op[(size_t)c * HW_] = gamma * (o + bv[c]) + xr[(size_t)c * HW_];
  }
}

// ---------------------------------------------------------------------------
extern "C" void kernel_launch(void* const* d_in, const int* in_sizes, int n_in,
                              void* d_out, int out_size, void* d_ws, size_t ws_size,
                              hipStream_t stream) {
  const float* x   = (const float*)d_in[0];
  const float* wq  = (const float*)d_in[1];
  const float* bq  = (const float*)d_in[2];
  const float* wk  = (const float*)d_in[3];
  const float* bk  = (const float*)d_in[4];
  const float* wv  = (const float*)d_in[5];
  const float* bv  = (const float*)d_in[6];
  const float* gam = (const float*)d_in[7];
  float* out = (float*)d_out;

  float* WT    = (float*)d_ws;                        // 2*64*32 = 4096 floats
  float* partE = WT + 4096;                           // 4*288*256 floats
  float* heat  = partE + (size_t)B_ * NCHUNK_ * 256;  // 4*256 floats

  k_prep   <<<1, 256, 0, stream>>>(wq, wk, WT);
  k_energy <<<dim3(NCHUNK_, B_), 512, 0, stream>>>(x, WT, bq, bk, partE);
  k_softmax<<<dim3(B_),          256, 0, stream>>>(partE, heat);
  k_mix    <<<dim3(HW_ / 16, B_), 256, 0, stream>>>(x, heat, wv, bv, gam, out);
}